// Round 11
// baseline (316.411 us; speedup 1.0000x reference)
//
#include <hip/hip_runtime.h>
#include <math.h>

#define HW 4096

typedef __attribute__((ext_vector_type(8))) short bh8;
typedef __attribute__((ext_vector_type(4))) float f32x4;
typedef unsigned int u32;
typedef unsigned short u16;

__device__ __forceinline__ u16 f2bf(float f) {
  union { float f; u32 u; } v; v.f = f;
  u32 u = v.u;
  return (u16)((u + 0x7FFFu + ((u >> 16) & 1u)) >> 16);
}
__device__ __forceinline__ float bf2f(u16 h) {
  union { u32 u; float f; } v; v.u = ((u32)h) << 16;
  return v.f;
}

// ---------------------------------------------------------------------------
// kv projection (+ fused conv-weight convert prologue).
// Branch 1 (spatial attn): K1 -> bf16 n-major (b,4096,64), V1 -> bf16
// ch-major (b,64,4096). Branch 2 (channel attn): bf16 ch-major.
// grid (64 nblk, 8 b), block 256
// ---------------------------------------------------------------------------
__global__ __launch_bounds__(256) void kv_proj(
    const float* __restrict__ xs,
    const float* __restrict__ w1, const float* __restrict__ b1,
    const float* __restrict__ w2, const float* __restrict__ b2,
    u32* __restrict__ Knm, u16* __restrict__ Vcm,
    u16* __restrict__ K2t, u16* __restrict__ V2t,
    const float* __restrict__ cw, const float* __restrict__ gamma,
    const float* __restrict__ beta, const float* __restrict__ mean,
    const float* __restrict__ var, u16* __restrict__ Wg,
    float* __restrict__ shb) {
  __shared__ float Ss[64][65];
  __shared__ float Ws[128 * 64];
  __shared__ u32 LtK[64][33];  // packed bf16x2 K rows, conflict-free pitch
  const int b = blockIdx.y, n0 = blockIdx.x * 64;
  const int t = threadIdx.x;
  const int lane_n = t & 63, jg = t >> 6;
  const int jbase = jg * 32;
  const float* xsb = xs + (size_t)b * 128 * HW;

  // ---- fused wcvt: conv_w (oc,ic,3,3) -> Wg[tap][oc][ic] bf16, BN folded ----
  {
    int gid = (blockIdx.y * 64 + blockIdx.x) * 256 + t;  // 0..131071
    for (int i = gid; i < 147456; i += 131072) {
      int tap = i >> 14, oc = (i >> 7) & 127, ic = i & 127;
      float sc = gamma[oc] * rsqrtf(var[oc] + 1e-5f);
      Wg[i] = f2bf(cw[((size_t)(oc * 128 + ic)) * 9 + tap] * sc);
    }
    if (gid < 128) {
      float sc = gamma[gid] * rsqrtf(var[gid] + 1e-5f);
      shb[gid] = beta[gid] - mean[gid] * sc;
    }
  }

  for (int br = 0; br < 2; ++br) {
    const float* W = br ? w2 : w1;
    const float* bias = br ? b2 : b1;
    const float* src = xsb + (br ? 64 * HW : 0);
    __syncthreads();
    for (int s = 0; s < 16; ++s) {
      int ch = s * 4 + jg;
      Ss[ch][lane_n] = src[(size_t)ch * HW + n0 + lane_n];
    }
    for (int i = t; i < 128 * 64; i += 256) Ws[i] = W[i];
    __syncthreads();

    float acc[32];
#pragma unroll
    for (int i = 0; i < 32; ++i) acc[i] = bias[jbase + i];
    for (int ch = 0; ch < 64; ++ch) {
      float s = Ss[ch][lane_n];
#pragma unroll
      for (int i = 0; i < 32; ++i) acc[i] = fmaf(Ws[(jbase + i) * 64 + ch], s, acc[i]);
    }

    if (br == 0) {
      if (jg < 2) {  // K channels jbase..jbase+31 -> pack to LDS
#pragma unroll
        for (int i2 = 0; i2 < 16; ++i2) {
          u32 p = (u32)f2bf(acc[2 * i2]) | ((u32)f2bf(acc[2 * i2 + 1]) << 16);
          LtK[lane_n][jg * 16 + i2] = p;
        }
      } else {  // V channels (jbase-64)..+31 -> bf16 ch-major global
#pragma unroll
        for (int i = 0; i < 32; ++i) {
          int ch = jbase - 64 + i;
          Vcm[((size_t)b * 64 + ch) * HW + n0 + lane_n] = f2bf(acc[i]);
        }
      }
      __syncthreads();
      // coalesced n-major K write: rows of 32 uints (64 bf16)
#pragma unroll
      for (int p = 0; p < 8; ++p) {
        int idx = p * 256 + t;
        int n = idx >> 5, cc = idx & 31;
        Knm[((size_t)b * HW + n0 + n) * 32 + cc] = LtK[n][cc];
      }
    } else {  // channel branch: bf16 ch-major K2t/V2t
      u16* Kt = K2t + (size_t)b * 64 * HW;
      u16* Vt = V2t + (size_t)b * 64 * HW;
#pragma unroll
      for (int i = 0; i < 32; ++i) {
        int j = jbase + i;
        u16* dst = (j < 64) ? (Kt + (size_t)j * HW) : (Vt + (size_t)(j - 64) * HW);
        dst[n0 + lane_n] = f2bf(acc[i]);
      }
    }
  }
}

// ---------------------------------------------------------------------------
// Fused dispatch: blocks x<64 run MFMA flash attention (r6 structure);
// blocks x==64 (one per b) run the channel-gram as a pure-MFMA, zero-LDS
// GEMM writing M directly (replaces chan_gram partials + chan_reduce).
// grid (65, 8 b), block 256
// ---------------------------------------------------------------------------
__device__ __forceinline__ void attn_step(
    const bh8* kf, const bh8* vf, const bh8 (&qb)[4][2],
    f32x4 (&O)[4][4], float (&lsum)[4], u16* Pw, int lq, int quad) {
  f32x4 S[2][4];
#pragma unroll
  for (int mt = 0; mt < 2; ++mt)
#pragma unroll
    for (int nt = 0; nt < 4; ++nt) {
      f32x4 a = (f32x4)(0.f);
      a = __builtin_amdgcn_mfma_f32_16x16x32_bf16(kf[mt * 2 + 0], qb[nt][0], a, 0, 0, 0);
      a = __builtin_amdgcn_mfma_f32_16x16x32_bf16(kf[mt * 2 + 1], qb[nt][1], a, 0, 0, 0);
      S[mt][nt] = a;
    }
#pragma unroll
  for (int mt = 0; mt < 2; ++mt)
#pragma unroll
    for (int nt = 0; nt < 4; ++nt) {
      float p0 = __expf(S[mt][nt][0] - 12.f);
      float p1 = __expf(S[mt][nt][1] - 12.f);
      float p2 = __expf(S[mt][nt][2] - 12.f);
      float p3 = __expf(S[mt][nt][3] - 12.f);
      lsum[nt] += (p0 + p1) + (p2 + p3);
      u32 lo = (u32)f2bf(p0) | ((u32)f2bf(p1) << 16);
      u32 hi = (u32)f2bf(p2) | ((u32)f2bf(p3) << 16);
      *(uint2*)&Pw[(nt * 16 + lq) * 36 + mt * 16 + quad * 4] = make_uint2(lo, hi);
    }
#pragma unroll
  for (int nt = 0; nt < 4; ++nt) {
    bh8 pb = *(const bh8*)&Pw[(nt * 16 + lq) * 36 + quad * 8];
#pragma unroll
    for (int ct = 0; ct < 4; ++ct)
      O[ct][nt] = __builtin_amdgcn_mfma_f32_16x16x32_bf16(vf[ct], pb, O[ct][nt], 0, 0, 0);
  }
}

#define LOADKV(KB, KF, VF)                                            \
  do {                                                                \
    const int n0_ = (KB) * 128;                                       \
    const u16* kr_ = Kb + (size_t)(n0_ + wb + lq) * 64 + quad * 8;    \
    KF[0] = *(const bh8*)(kr_);                                       \
    KF[1] = *(const bh8*)(kr_ + 32);                                  \
    KF[2] = *(const bh8*)(kr_ + 1024);                                \
    KF[3] = *(const bh8*)(kr_ + 1056);                                \
    const u16* vr_ = Vb + (size_t)lq * HW + n0_ + wb + quad * 8;      \
    VF[0] = *(const bh8*)(vr_);                                       \
    VF[1] = *(const bh8*)(vr_ + 16 * HW);                             \
    VF[2] = *(const bh8*)(vr_ + 32 * HW);                             \
    VF[3] = *(const bh8*)(vr_ + 48 * HW);                             \
  } while (0)

__global__ __launch_bounds__(256, 2) void attn_gram(
    const float* __restrict__ xu, const float* __restrict__ xs,
    const u16* __restrict__ Knm, const u16* __restrict__ Vcm,
    u16* __restrict__ xcat,
    const u16* __restrict__ K2t, float* __restrict__ M) {
  __shared__ __align__(16) u16 SMEM[18432];  // 36864 B (attn path only)
  const int b = blockIdx.y;
  const int t = threadIdx.x;
  const int wq = t >> 6, lane = t & 63, lq = lane & 15, quad = lane >> 4;

  if (blockIdx.x == 64) {
    // ------- channel gram, pure MFMA, no LDS: M[c][d] = sum_n u2*k2 -------
    // wave wq: c-tile wq*16..+16 (A, m=c), all 64 d (4 B-tiles), k = n.
    const float* u2row = xu + ((size_t)b * 128 + 64 + wq * 16 + lq) * HW;
    const u16* k2 = K2t + (size_t)b * 64 * HW;
    f32x4 acc[4];
#pragma unroll
    for (int nt = 0; nt < 4; ++nt) acc[nt] = (f32x4)(0.f);
#pragma unroll 2
    for (int ch = 0; ch < 128; ++ch) {
      int n0 = ch * 32 + quad * 8;
      float4 a0 = *(const float4*)(u2row + n0);
      float4 a1 = *(const float4*)(u2row + n0 + 4);
      bh8 af;
      af[0] = (short)f2bf(a0.x); af[1] = (short)f2bf(a0.y);
      af[2] = (short)f2bf(a0.z); af[3] = (short)f2bf(a0.w);
      af[4] = (short)f2bf(a1.x); af[5] = (short)f2bf(a1.y);
      af[6] = (short)f2bf(a1.z); af[7] = (short)f2bf(a1.w);
#pragma unroll
      for (int nt = 0; nt < 4; ++nt) {
        bh8 bf = *(const bh8*)(k2 + (size_t)(nt * 16 + lq) * HW + n0);
        acc[nt] = __builtin_amdgcn_mfma_f32_16x16x32_bf16(af, bf, acc[nt], 0, 0, 0);
      }
    }
    float* Mb = M + b * 4096;
#pragma unroll
    for (int nt = 0; nt < 4; ++nt)
#pragma unroll
      for (int r = 0; r < 4; ++r)
        Mb[(wq * 16 + quad * 4 + r) * 64 + nt * 16 + lq] = acc[nt][r];
    return;
  }

  // ---------------- attention path (r6 structure) ----------------
  const int q0 = blockIdx.x * 64;
  const int wb = wq * 32;  // wave's key-slice base within a 128-key tile
  const float* xub = xu + (size_t)b * 128 * HW;
  const float* xsb = xs + (size_t)b * 128 * HW;
  const u16* Kb = Knm + (size_t)b * HW * 64;
  const u16* Vb = Vcm + (size_t)b * 64 * HW;
  u16* Pw = SMEM + wq * 64 * 36;  // wave-private P (q,k) tile

  // Q B-fragments: all 64 q x 64 ch per wave (B[n=q][k=ch])
  bh8 qb[4][2];
#pragma unroll
  for (int nt = 0; nt < 4; ++nt)
#pragma unroll
    for (int s = 0; s < 2; ++s)
#pragma unroll
      for (int j = 0; j < 8; ++j) {
        int ch = s * 32 + quad * 8 + j;
        qb[nt][s][j] = (short)f2bf(xub[(size_t)ch * HW + q0 + nt * 16 + lq]);
      }

  f32x4 O[4][4];  // [ct: ch-tile][nt: q-tile], C: row=ch_local, col=q_local
#pragma unroll
  for (int ct = 0; ct < 4; ++ct)
#pragma unroll
    for (int nt = 0; nt < 4; ++nt) O[ct][nt] = (f32x4)(0.f);
  float lsum[4] = {0.f, 0.f, 0.f, 0.f};

  bh8 kfa[4], vfa[4], kfb[4], vfb[4];
  LOADKV(0, kfa, vfa);
  for (int kb = 0; kb < 32; kb += 2) {
    LOADKV(kb + 1, kfb, vfb);
    attn_step(kfa, vfa, qb, O, lsum, Pw, lq, quad);
    if (kb + 2 < 32) LOADKV(kb + 2, kfa, vfa);
    attn_step(kfb, vfb, qb, O, lsum, Pw, lq, quad);
  }

  // ---- epilogue: cross-wave reduce, normalize, shortcut, bf16 store ----
#pragma unroll
  for (int nt = 0; nt < 4; ++nt) {
    lsum[nt] += __shfl_xor(lsum[nt], 16);
    lsum[nt] += __shfl_xor(lsum[nt], 32);
  }
  __syncthreads();  // all waves done with their Pw before SMEM reuse
  float* Posc = (float*)SMEM;            // [4 waves][32 ch][68 q] = 34816 B
  float* Lred = (float*)(SMEM + 17408);  // [4 waves][4 nt][16 lq] = 1024 B
  if (quad == 0) {
#pragma unroll
    for (int nt = 0; nt < 4; ++nt) Lred[(wq * 4 + nt) * 16 + lq] = lsum[nt];
  }

  const int q = t & 63, cg = t >> 6;
#pragma unroll
  for (int rh = 0; rh < 2; ++rh) {
    if (rh) __syncthreads();  // previous half's readers done
#pragma unroll
    for (int c2 = 0; c2 < 2; ++c2)
#pragma unroll
      for (int nt = 0; nt < 4; ++nt)
#pragma unroll
        for (int r = 0; r < 4; ++r)
          Posc[(wq * 32 + c2 * 16 + quad * 4 + r) * 68 + nt * 16 + lq] =
              O[rh * 2 + c2][nt][r];
    __syncthreads();
    float li = 0.f;
#pragma unroll
    for (int w2 = 0; w2 < 4; ++w2) li += Lred[w2 * 64 + q];
    float inv = 1.f / li;
    u16 h[8];
#pragma unroll
    for (int i = 0; i < 8; ++i) {
      int chl = cg * 8 + i;
      float s = 0.f;
#pragma unroll
      for (int w2 = 0; w2 < 4; ++w2) s += Posc[(w2 * 32 + chl) * 68 + q];
      int ch = rh * 32 + chl;
      size_t g = (size_t)ch * HW + q0 + q;
      h[i] = f2bf(s * inv + xub[g] + xsb[g]);
    }
    u32 pk[4];
#pragma unroll
    for (int j = 0; j < 4; ++j) pk[j] = (u32)h[2 * j] | ((u32)h[2 * j + 1] << 16);
    u16* ob = xcat + ((size_t)b * HW + q0 + q) * 128 + rh * 32 + cg * 8;
    *(uint4*)ob = make_uint4(pk[0], pk[1], pk[2], pk[3]);
  }
}

// ---------------------------------------------------------------------------
// chan_apply, MFMA version. Softmax over c of M[b] (unnormalized exp stored
// transposed bf16 [d][72] for B-frags); V tile bf16 [n][72] (A-frags);
// cout = (V·E)/sm + shortcut2, bf16 n-major store via LDS bounce.
// grid (64 nblk, 8 b), block 256
// ---------------------------------------------------------------------------
__global__ __launch_bounds__(256) void chan_apply(
    const u16* __restrict__ V2t, const float* __restrict__ M,
    const float* __restrict__ xu, const float* __restrict__ xs,
    u16* __restrict__ xcat) {
  __shared__ __align__(16) u16 SM[9216];  // Vsm [64][72] + Ast [64][72] = 18432 B
  __shared__ float red1[4][64], red2[4][64];
  const int b = blockIdx.y, n0 = blockIdx.x * 64, t = threadIdx.x;
  const int wq = t >> 6, lane = t & 63, lq = lane & 15, quad = lane >> 4;
  u16* Vsm = SM;          // [n][72] bf16
  u16* Ast = SM + 4608;   // [d][72] bf16 (exp, unnormalized)

  // stage V: Vsm[n][c] = V2t[b][c][n0+n]  (both bf16, coalesced reads)
  for (int s = 0; s < 16; ++s) {
    int c = s * 4 + wq;
    Vsm[lane * 72 + c] = V2t[((size_t)b * 64 + c) * HW + n0 + lane];
  }
  // softmax over c for d = lane; this thread owns c in [wq*16, wq*16+16)
  {
    const float* Mb = M + b * 4096;
    float v[16];
    float mx = -1e30f;
#pragma unroll
    for (int i = 0; i < 16; ++i) {
      v[i] = Mb[(wq * 16 + i) * 64 + lane];
      mx = fmaxf(mx, v[i]);
    }
    red1[wq][lane] = mx;
    __syncthreads();
    mx = fmaxf(fmaxf(red1[0][lane], red1[1][lane]),
               fmaxf(red1[2][lane], red1[3][lane]));
    float se = 0.f;
#pragma unroll
    for (int i = 0; i < 16; ++i) {
      float e = __expf(v[i] - mx);
      se += e;
      Ast[lane * 72 + wq * 16 + i] = f2bf(e);
    }
    red2[wq][lane] = se;
  }
  __syncthreads();

  // MFMA: m = n (wave's 16 rows), n-op = d (4 tiles), k = c (2 chunks)
  f32x4 acc[4];
#pragma unroll
  for (int nt = 0; nt < 4; ++nt) acc[nt] = (f32x4)(0.f);
#pragma unroll
  for (int ks = 0; ks < 2; ++ks) {
    bh8 af = *(const bh8*)&Vsm[(wq * 16 + lq) * 72 + ks * 32 + quad * 8];
#pragma unroll
    for (int nt = 0; nt < 4; ++nt) {
      bh8 bf = *(const bh8*)&Ast[(nt * 16 + lq) * 72 + ks * 32 + quad * 8];
      acc[nt] = __builtin_amdgcn_mfma_f32_16x16x32_bf16(af, bf, acc[nt], 0, 0, 0);
    }
  }

  // bounce C through LDS for packed n-major stores
  __syncthreads();
  float* Bounce = (float*)SM;  // [64 n][68 d] = 17408 B (overlays Vsm+Ast)
#pragma unroll
  for (int nt = 0; nt < 4; ++nt)
#pragma unroll
    for (int r = 0; r < 4; ++r)
      Bounce[(wq * 16 + quad * 4 + r) * 68 + nt * 16 + lq] = acc[nt][r];
  __syncthreads();

  const float* xub = xu + ((size_t)b * 128 + 64) * HW;
  const float* xsb = xs + ((size_t)b * 128 + 64) * HW;
  const int n = n0 + lane;
  u16 hv[16];
#pragma unroll
  for (int i = 0; i < 16; ++i) {
    int d = wq * 16 + i;
    float sm = red2[0][d] + red2[1][d] + red2[2][d] + red2[3][d];
    float val = Bounce[lane * 68 + d] / sm + xub[(size_t)d * HW + n] + xsb[(size_t)d * HW + n];
    hv[i] = f2bf(val);
  }
  u32 pk[8];
#pragma unroll
  for (int j = 0; j < 8; ++j) pk[j] = (u32)hv[2 * j] | ((u32)hv[2 * j + 1] << 16);
  u16* ob = xcat + ((size_t)b * HW + n) * 128 + 64 + wq * 16;
  *(uint4*)(ob) = make_uint4(pk[0], pk[1], pk[2], pk[3]);
  *(uint4*)(ob + 8) = make_uint4(pk[4], pk[5], pk[6], pk[7]);
}

// ---------------------------------------------------------------------------
// Implicit-GEMM 3x3 conv via bf16 MFMA + fused BN(folded) + ReLU.
// Block: 512 thr = 8 waves (2 waves/SIMD). Tile: 128 spatial x 128 oc.
// grid (32 hblk, 8 b)
// ---------------------------------------------------------------------------
__global__ __launch_bounds__(512) void conv_mfma(
    const u16* __restrict__ X, const u16* __restrict__ Wg,
    const float* __restrict__ shb, float* __restrict__ out) {
  __shared__ __align__(16) u16 In[4 * 66 * 136];
  __shared__ __align__(16) u16 Wt[2][128 * 136];
  const int b = blockIdx.y, h0 = blockIdx.x * 2;
  const int t = threadIdx.x;
  const int wq = t >> 6, lane = t & 63, lq = lane & 15, quad = lane >> 4;
  const int nb = (wq & 1) * 64;       // oc-half base
  const int mb = (wq >> 1) * 2;       // m-tile pair base
  const u16* Xb = X + (size_t)b * HW * 128;

  // zero w-halo cells (iw = 0 and 65 for each ih)
  if (t < 128) {
    int ih = t >> 5, iwsel = (t >> 4) & 1, ck = t & 15;
    int iw = iwsel ? 65 : 0;
    *(uint4*)&In[(ih * 66 + iw) * 136 + ck * 8] = make_uint4(0, 0, 0, 0);
  }
  // stage input rows (zero h-halo out of range); 512 threads
  for (int ih = 0; ih < 4; ++ih) {
    int h = h0 - 1 + ih;
    bool ok = (h >= 0 && h < 64);
    const u16* src = Xb + (size_t)h * 64 * 128;
#pragma unroll
    for (int p = 0; p < 2; ++p) {
      int idx = p * 512 + t;
      int row = idx >> 4, ck = idx & 15;
      uint4 d = make_uint4(0, 0, 0, 0);
      if (ok) d = *(const uint4*)(src + (size_t)row * 128 + ck * 8);
      *(uint4*)&In[(ih * 66 + 1 + row) * 136 + ck * 8] = d;
    }
  }
  // stage tap-0 weights into buffer 0 (2048 uint4 over 512 threads = 4 passes)
  {
    const u16* src = Wg;
#pragma unroll
    for (int p = 0; p < 4; ++p) {
      int idx = p * 512 + t;
      int oc = idx >> 4, ck = idx & 15;
      uint4 d = *(const uint4*)(src + oc * 128 + ck * 8);
      *(uint4*)&Wt[0][oc * 136 + ck * 8] = d;
    }
  }
  __syncthreads();

  f32x4 acc[2][4];
#pragma unroll
  for (int mt = 0; mt < 2; ++mt)
#pragma unroll
    for (int nt = 0; nt < 4; ++nt) acc[mt][nt] = (f32x4)(0.f);

  for (int tap = 0; tap < 9; ++tap) {
    const int cur = tap & 1;
    if (tap < 8) {  // prefetch next tap into the other buffer
      const u16* src = Wg + (size_t)(tap + 1) * 128 * 128;
#pragma unroll
      for (int p = 0; p < 4; ++p) {
        int idx = p * 512 + t;
        int oc = idx >> 4, ck = idx & 15;
        uint4 d = *(const uint4*)(src + oc * 128 + ck * 8);
        *(uint4*)&Wt[cur ^ 1][oc * 136 + ck * 8] = d;
      }
    }
    const int dh = tap / 3, dw = tap - 3 * dh;
    const u16* Wc = &Wt[cur][0];
#pragma unroll
    for (int c = 0; c < 4; ++c) {
      bh8 bf[4];
#pragma unroll
      for (int nt = 0; nt < 4; ++nt)
        bf[nt] = *(const bh8*)&Wc[(nb + nt * 16 + lq) * 136 + c * 32 + quad * 8];
#pragma unroll
      for (int mt = 0; mt < 2; ++mt) {
        int s = (mb + mt) * 16 + lq;
        int ih = (s >> 6) + dh, iw = (s & 63) + dw;
        bh8 af = *(const bh8*)&In[(ih * 66 + iw) * 136 + c * 32 + quad * 8];
#pragma unroll
        for (int nt = 0; nt < 4; ++nt)
          acc[mt][nt] = __builtin_amdgcn_mfma_f32_16x16x32_bf16(af, bf[nt], acc[mt][nt], 0, 0, 0);
      }
    }
    __syncthreads();
  }

  // epilogue: +bias, ReLU, dense float4 stores
  float shv[4];
#pragma unroll
  for (int nt = 0; nt < 4; ++nt) shv[nt] = shb[nb + nt * 16 + lq];
#pragma unroll
  for (int mt = 0; mt < 2; ++mt) {
    int mtile = mb + mt;
    int h = h0 + (mtile >> 2);
    int w0 = ((mtile & 3) * 16) + quad * 4;
#pragma unroll
    for (int nt = 0; nt < 4; ++nt) {
      int oc = nb + nt * 16 + lq;
      float4 v;
      v.x = fmaxf(acc[mt][nt][0] + shv[nt], 0.f);
      v.y = fmaxf(acc[mt][nt][1] + shv[nt], 0.f);
      v.z = fmaxf(acc[mt][nt][2] + shv[nt], 0.f);
      v.w = fmaxf(acc[mt][nt][3] + shv[nt], 0.f);
      *(float4*)&out[((size_t)b * 128 + oc) * HW + h * 64 + w0] = v;
    }
  }
}

// ---------------------------------------------------------------------------
extern "C" void kernel_launch(void* const* d_in, const int* in_sizes, int n_in,
                              void* d_out, int out_size, void* d_ws, size_t ws_size,
                              hipStream_t stream) {
  const float* x_up   = (const float*)d_in[0];
  const float* x_skip = (const float*)d_in[1];
  const float* kv1_w  = (const float*)d_in[2];
  const float* kv1_b  = (const float*)d_in[3];
  const float* kv2_w  = (const float*)d_in[4];
  const float* kv2_b  = (const float*)d_in[5];
  const float* conv_w = (const float*)d_in[6];
  const float* bn_g   = (const float*)d_in[7];
  const float* bn_b   = (const float*)d_in[8];
  const float* bn_m   = (const float*)d_in[9];
  const float* bn_v   = (const float*)d_in[10];
  float* out = (float*)d_out;

  char* ws = (char*)d_ws;
  const size_t XCATB_B = (size_t)8 * HW * 128 * 2;  // 8.39 MB bf16 n-major
  const size_t KV16_B  = (size_t)8 * 64 * HW * 2;   // 4.19 MB
  size_t off = 0;
  u16*   xcat = (u16*)(ws + off);   off += XCATB_B;
  u16*   K2t  = (u16*)(ws + off);   off += KV16_B;
  u16*   V2t  = (u16*)(ws + off);   off += KV16_B;
  u32*   Knm  = (u32*)(ws + off);   off += KV16_B;
  u16*   Vcm  = (u16*)(ws + off);   off += KV16_B;
  float* M    = (float*)(ws + off); off += (size_t)8 * 4096 * 4;
  u16*   Wg   = (u16*)(ws + off);   off += (size_t)9 * 128 * 128 * 2;
  float* shb  = (float*)(ws + off); off += 512;
  // total ~25.6 MB

  kv_proj<<<dim3(64, 8), 256, 0, stream>>>(x_skip, kv1_w, kv1_b, kv2_w, kv2_b,
                                           Knm, Vcm, K2t, V2t,
                                           conv_w, bn_g, bn_b, bn_m, bn_v, Wg, shb);
  attn_gram<<<dim3(65, 8), 256, 0, stream>>>(x_up, x_skip, (const u16*)Knm, Vcm,
                                             xcat, K2t, M);
  chan_apply<<<dim3(64, 8), 256, 0, stream>>>(V2t, M, x_up, x_skip, xcat);
  conv_mfma<<<dim3(32, 8), 512, 0, stream>>>(xcat, Wg, shb, out);
}